// Round 17
// baseline (36.512 us; speedup 1.0000x reference)
//
#include <hip/hip_runtime.h>
#include <math.h>

#define NCTX 1024
#define DIN 512
#define NH 8
#define DH 64

typedef float f32x16 __attribute__((ext_vector_type(16)));
typedef short bf16x8 __attribute__((ext_vector_type(8)));
typedef int i32x4 __attribute__((ext_vector_type(4)));

// ws byte offsets: Qf 4MB | Kf 4MB | Vf 4MB | V0f 8KB
#define QF_OFF 0
#define KF_OFF (4u * 1024u * 1024u)
#define VF_OFF (8u * 1024u * 1024u)
#define V0_OFF (12u * 1024u * 1024u)

__device__ __forceinline__ bf16x8 asbf(i32x4 v) {
  union { i32x4 i; bf16x8 h; } u;
  u.i = v;
  return u.h;
}

__device__ __forceinline__ bf16x8 mk8(unsigned a, unsigned b, unsigned c,
                                      unsigned d) {
  union { unsigned u[4]; bf16x8 h; } x;
  x.u[0] = a; x.u[1] = b; x.u[2] = c; x.u[3] = d;
  return x.h;
}

__device__ __forceinline__ unsigned cvtpk(float lo, float hi_) {
  unsigned r;
  asm("v_cvt_pk_bf16_f32 %0, %1, %2" : "=v"(r) : "v"(lo), "v"(hi_));
  return r;
}

__device__ __forceinline__ void softmax8(const float* __restrict__ w,
                                         float* __restrict__ p) {
  float mx = w[0];
#pragma unroll
  for (int v = 1; v < 8; ++v) mx = fmaxf(mx, w[v]);
  float s = 0.f;
#pragma unroll
  for (int v = 0; v < 8; ++v) { p[v] = expf(w[v] - mx); s += p[v]; }
  const float inv = 1.f / s;
#pragma unroll
  for (int v = 0; v < 8; ++v) p[v] *= inv;
}

// Fragment layouts:
// Kf[bi][t][pq][kk][lane] : K[32pq+l%32][16kk+8*(l>>5)+i]   (A-op of St)
// Qf[bi][t][qq][kk][lane] : Q[32qq+l%32][16kk+8*(l>>5)+i]   (B-op of St)
// Vf[bi][t][pq][2kk2+hh][lane] : V[32pq+16kk2+8*(l>>5)+i][32hh+l%32] (B-op PV)
__global__ __launch_bounds__(256) void prep_kernel(
    const float* __restrict__ x, const float* __restrict__ WKw,
    const float* __restrict__ WQw, const float* __restrict__ WVw,
    const float* __restrict__ Wpred, short* __restrict__ Qf,
    short* __restrict__ Kf, short* __restrict__ Vf, float* __restrict__ V0f) {
  const int t = blockIdx.x, ih = blockIdx.y, b = blockIdx.z;
  const int bi = b * NH + ih;
  const int tid = threadIdx.x;

  // bf16 tiles, 128B rows, XOR-swizzled: byte = row*128 + (col2 ^ ((row&7)<<4))
  __shared__ alignas(16) char smem[5 * 8192];
  char* const Ksb = smem;              // K row-major [p][h]
  char* const Vtb = smem + 8192;       // V col-major [h][p]
  char* const Q0b = smem + 16384;      // Q0 row-major [q][e]
  char* const WpT = smem + 24576;      // Wp transposed [f][e]
  char* const Qsb = smem + 32768;      // Q row-major [q][f]

  // ---- Wp softmax -> WpT (transposed, bf16, swizzled) ----
  {
    const int e = tid >> 2, sg = tid & 3;
    const float* wr = Wpred + (size_t)(ih * 64 + e) * 64 + sg * 16;
    float e16[16];
    float mx = -1e30f;
#pragma unroll
    for (int j = 0; j < 16; ++j) { e16[j] = wr[j]; mx = fmaxf(mx, e16[j]); }
    mx = fmaxf(mx, __shfl_xor(mx, 1, 4));
    mx = fmaxf(mx, __shfl_xor(mx, 2, 4));
    float s = 0.f;
#pragma unroll
    for (int j = 0; j < 16; ++j) { e16[j] = __expf(e16[j] - mx); s += e16[j]; }
    s += __shfl_xor(s, 1, 4);
    s += __shfl_xor(s, 2, 4);
    const float inv = 1.f / s;
#pragma unroll
    for (int j = 0; j < 16; ++j) {
      const int f = sg * 16 + j;
      const unsigned pz = cvtpk(e16[j] * inv, e16[j] * inv);
      *(unsigned short*)&WpT[f * 128 + ((2 * e) ^ ((f & 7) << 4))] =
          (unsigned short)pz;
    }
  }

  float pk[8], pq8[8], pv[8];
  {
    float w[8];
#pragma unroll
    for (int v = 0; v < 8; ++v) w[v] = WKw[ih * 8 + v];
    softmax8(w, pk);
#pragma unroll
    for (int v = 0; v < 8; ++v) w[v] = WQw[ih * 8 + v];
    softmax8(w, pq8);
#pragma unroll
    for (int v = 0; v < 8; ++v) w[v] = WVw[ih * 8 + v];
    softmax8(w, pv);
  }

  // ---- Stage A: 4x4 register block of the mixes, float4 x loads ----
  const int rg = tid >> 4, eg = tid & 15;
  const int r0 = rg * 4, e0 = eg * 4;
  float ka[4][4], qa[4][4], va[4][4];
#pragma unroll
  for (int i2 = 0; i2 < 4; ++i2)
#pragma unroll
    for (int j = 0; j < 4; ++j) { ka[i2][j] = 0.f; qa[i2][j] = 0.f; va[i2][j] = 0.f; }

  const float* xb = x + ((size_t)(b * NCTX + t * 64 + r0)) * DIN + e0;
#pragma unroll
  for (int v = 0; v < 8; ++v) {
#pragma unroll
    for (int i2 = 0; i2 < 4; ++i2) {
      const float4 xv = *(const float4*)(xb + (size_t)i2 * DIN + v * 64);
      ka[i2][0] = fmaf(pk[v], xv.x, ka[i2][0]);
      ka[i2][1] = fmaf(pk[v], xv.y, ka[i2][1]);
      ka[i2][2] = fmaf(pk[v], xv.z, ka[i2][2]);
      ka[i2][3] = fmaf(pk[v], xv.w, ka[i2][3]);
      qa[i2][0] = fmaf(pq8[v], xv.x, qa[i2][0]);
      qa[i2][1] = fmaf(pq8[v], xv.y, qa[i2][1]);
      qa[i2][2] = fmaf(pq8[v], xv.z, qa[i2][2]);
      qa[i2][3] = fmaf(pq8[v], xv.w, qa[i2][3]);
      va[i2][0] = fmaf(pv[v], xv.x, va[i2][0]);
      va[i2][1] = fmaf(pv[v], xv.y, va[i2][1]);
      va[i2][2] = fmaf(pv[v], xv.z, va[i2][2]);
      va[i2][3] = fmaf(pv[v], xv.w, va[i2][3]);
    }
  }

  // V[0][*] in f32 for the attn correction term
  if (t == 0 && rg == 0) {
    *(float4*)(V0f + bi * 64 + e0) =
        make_float4(va[0][0], va[0][1], va[0][2], va[0][3]);
  }

  // bf16 LDS writes (K, Q0 row-major; V col-major)
#pragma unroll
  for (int i2 = 0; i2 < 4; ++i2) {
    const int r = r0 + i2;
    const int boff = (2 * e0) ^ ((r & 7) << 4);
    *(uint2*)&Ksb[r * 128 + boff] =
        make_uint2(cvtpk(ka[i2][0], ka[i2][1]), cvtpk(ka[i2][2], ka[i2][3]));
    *(uint2*)&Q0b[r * 128 + boff] =
        make_uint2(cvtpk(qa[i2][0], qa[i2][1]), cvtpk(qa[i2][2], qa[i2][3]));
  }
#pragma unroll
  for (int j = 0; j < 4; ++j) {
    const int rr = e0 + j;
    *(uint2*)&Vtb[rr * 128 + ((2 * r0) ^ ((rr & 7) << 4))] =
        make_uint2(cvtpk(va[0][j], va[1][j]), cvtpk(va[2][j], va[3][j]));
  }
  __syncthreads();

  const int wv = tid >> 6;
  const int l = tid & 63;
  const int lm = l & 31;
  const int hi = l >> 5;

  // ---- K/V fragment emission ----
  const size_t fbase = (size_t)bi * 8192 + (size_t)t * 512;
#pragma unroll
  for (int c = 0; c < 2; ++c) {
    const int idx = c * 256 + tid;
    const int pq = idx >> 8, j = (idx >> 6) & 3, ll = idx & 63;
    const int krow = 32 * pq + (ll & 31);
    const i32x4 kfr = *(const i32x4*)
        &Ksb[krow * 128 + ((32 * j + 16 * (ll >> 5)) ^ ((krow & 7) << 4))];
    ((i32x4*)Kf)[fbase + idx] = kfr;
    const int vrow = 32 * (j & 1) + (ll & 31);
    const i32x4 vfr = *(const i32x4*)
        &Vtb[vrow * 128 +
             ((64 * pq + 32 * (j >> 1) + 16 * (ll >> 5)) ^ ((vrow & 7) << 4))];
    ((i32x4*)Vf)[fbase + idx] = vfr;
  }

  // ---- Q = Q0 @ Wp via MFMA (wave quadrant qq x ff) ----
  {
    const int qq = wv & 1, ff = wv >> 1;
    f32x16 dreg;
#pragma unroll
    for (int r = 0; r < 16; ++r) dreg[r] = 0.f;
    const int arow = 32 * qq + lm;
    const int brow = 32 * ff + lm;
#pragma unroll
    for (int kk = 0; kk < 4; ++kk) {
      const i32x4 af = *(const i32x4*)
          &Q0b[arow * 128 + ((32 * kk + 16 * hi) ^ ((arow & 7) << 4))];
      const i32x4 bfr = *(const i32x4*)
          &WpT[brow * 128 + ((32 * kk + 16 * hi) ^ ((brow & 7) << 4))];
      dreg = __builtin_amdgcn_mfma_f32_32x32x16_bf16(asbf(af), asbf(bfr),
                                                     dreg, 0, 0, 0);
    }
#pragma unroll
    for (int r = 0; r < 16; ++r) {
      const int q = 32 * qq + (r & 3) + 8 * (r >> 2) + 4 * hi;
      const int f = 32 * ff + lm;
      const unsigned pz = cvtpk(dreg[r], dreg[r]);
      *(unsigned short*)&Qsb[q * 128 + ((2 * f) ^ ((q & 7) << 4))] =
          (unsigned short)pz;
    }
  }
  __syncthreads();

  // ---- Q fragment emission ----
#pragma unroll
  for (int c = 0; c < 2; ++c) {
    const int idx = c * 256 + tid;
    const int qq2 = idx >> 8, kk = (idx >> 6) & 3, ll = idx & 63;
    const int row = 32 * qq2 + (ll & 31);
    const i32x4 qfr = *(const i32x4*)
        &Qsb[row * 128 + ((32 * kk + 16 * (ll >> 5)) ^ ((row & 7) << 4))];
    ((i32x4*)Qf)[fbase + idx] = qfr;
  }
}

// Transform constants: log2 domain if the raw builtins exist, else natural.
#if __has_builtin(__builtin_amdgcn_exp2f) && __has_builtin(__builtin_amdgcn_logf)
#define T_LOG(x) __builtin_amdgcn_logf(x)
#define T_EXP(x) __builtin_amdgcn_exp2f(x)
#define T_L 1.7628215e-4f   /* 0.125/(1023*ln2) */
#define T_DIAG (-0.36067376f) /* -0.25*log2(e) */
#else
#define T_LOG(x) __logf(x)
#define T_EXP(x) __expf(x)
#define T_L 1.2219941e-4f   /* 0.125/1023 */
#define T_DIAG (-0.25f)
#endif

// Kernel 2: MFMA attention — design-matrix cell (parity-split, side-chain).
// Grid 1024: bx = a*32 + bi; qt = (a<16)? 15-(a>>1) : (a-16)>>1; qq = a&1.
// Per-CU blocks {c,c+256,c+512,c+768} sum to exactly 34 steps (balanced).
// Block = (bi, qt, qq), 4 waves: pq = wv&1 (p-row half), ph = wv>>1
// (p-tile parity: wave ph does t = ph, ph+2, ... <= qt) -> 16 waves/CU.
// __launch_bounds__(256,1) pins the 128-VGPR budget (r11 proved this
// spelling is spill-safe; live state ~115).
// KEEPS the full srw/pre0 side-chain + 1e-20 epsilons + p0 correction:
// r15/r16 proved removing it costs +3.3us (its independent VALU adds pad
// the serial log->exp chain). r10 tested this structure WITHOUT the
// side-chain (confounded); this is the clean test.
__global__ __launch_bounds__(256, 1) void attn_kernel(
    const short* __restrict__ Qf, const short* __restrict__ Kf,
    const short* __restrict__ Vf, const float* __restrict__ V0f,
    float* __restrict__ out) {
  const int bx = blockIdx.x;
  const int a = bx >> 5;     // 0..31
  const int bi = bx & 31;
  const int qt = (a < 16) ? (15 - (a >> 1)) : ((a - 16) >> 1);
  const int qq = a & 1;
  const int b = bi >> 3, ih = bi & 7;
  const int tid = threadIdx.x;
  const int wv = tid >> 6;   // 0..3
  const int pq = wv & 1;
  const int ph = wv >> 1;    // p-tile parity
  const int l = tid & 63;
  const int hi = l >> 5;
  const int lm = l & 31;

  __shared__ float nbuf[3][32][64];
  __shared__ float rdn[4][32];
  __shared__ float rsw[4][32];
  __shared__ float rp0[32];
  __shared__ float rdw[32];
  __shared__ float rinv[32];

  const i32x4* Qp = (const i32x4*)Qf + (size_t)bi * 8192 + (size_t)qt * 512 +
                    qq * 256;
  const i32x4* Kp = (const i32x4*)Kf + (size_t)bi * 8192 + pq * 256;
  const i32x4* Vp = (const i32x4*)Vf + (size_t)bi * 8192 + pq * 256;

  bf16x8 qfr[4];
#pragma unroll
  for (int kk = 0; kk < 4; ++kk) qfr[kk] = asbf(Qp[kk * 64 + l]);

  const float v0a = V0f[bi * 64 + lm];
  const float v0b = V0f[bi * 64 + 32 + lm];

  f32x16 num0, num1, st;
#pragma unroll
  for (int r = 0; r < 16; ++r) { num0[r] = 0.f; num1[r] = 0.f; }
  float den = 0.f, srw = 0.f, pre0 = 0.f;
  const int qg = qt * 64 + 32 * qq + lm;
  const int qpb = qg - 32 * pq - 4 * hi;  // D0 = qpb - 64*t

  i32x4 kK[4], vV[4];

#define LOADK(PT)                                                       \
  do {                                                                  \
    const size_t o_ = (size_t)(PT) * 512;                               \
    _Pragma("unroll") for (int kk = 0; kk < 4; ++kk)                    \
        kK[kk] = Kp[o_ + kk * 64 + l];                                  \
  } while (0)

#define LOADV(PT)                                                       \
  do {                                                                  \
    const size_t o_ = (size_t)(PT) * 512;                               \
    _Pragma("unroll") for (int j = 0; j < 4; ++j)                       \
        vV[j] = Vp[o_ + j * 64 + l];                                    \
  } while (0)

#define QKSTEP()                                                             \
  do {                                                                       \
    _Pragma("unroll") for (int r = 0; r < 16; ++r) st[r] = 0.f;              \
    __builtin_amdgcn_s_setprio(1);                                           \
    _Pragma("unroll") for (int kk = 0; kk < 4; ++kk) st =                    \
        __builtin_amdgcn_mfma_f32_32x32x16_bf16(asbf(kK[kk]), qfr[kk],       \
                                                st, 0, 0, 0);                \
    __builtin_amdgcn_s_setprio(0);                                           \
  } while (0)

#define REPACK_PV()                                                          \
  do {                                                                       \
    asm("v_permlane32_swap_b32 %0, %1" : "+v"(P0), "+v"(P2));                \
    asm("v_permlane32_swap_b32 %0, %1" : "+v"(P1), "+v"(P3));                \
    asm("v_permlane32_swap_b32 %0, %1" : "+v"(P4), "+v"(P6));                \
    asm("v_permlane32_swap_b32 %0, %1" : "+v"(P5), "+v"(P7));                \
    const bf16x8 wf0 = mk8(P0, P1, P2, P3);                                  \
    const bf16x8 wf1 = mk8(P4, P5, P6, P7);                                  \
    __builtin_amdgcn_s_setprio(1);                                           \
    num0 = __builtin_amdgcn_mfma_f32_32x32x16_bf16(wf0, asbf(vV[0]),         \
                                                   num0, 0, 0, 0);           \
    num1 = __builtin_amdgcn_mfma_f32_32x32x16_bf16(wf0, asbf(vV[1]),         \
                                                   num1, 0, 0, 0);           \
    num0 = __builtin_amdgcn_mfma_f32_32x32x16_bf16(wf1, asbf(vV[2]),         \
                                                   num0, 0, 0, 0);           \
    num1 = __builtin_amdgcn_mfma_f32_32x32x16_bf16(wf1, asbf(vV[3]),         \
                                                   num1, 0, 0, 0);           \
    __builtin_amdgcn_s_setprio(0);                                           \
  } while (0)

  if (ph <= qt) {
    // Prologue: st = S(ph), kK = K(ph+2), vV = V(ph).
    LOADK(ph);
    LOADV(ph);
    QKSTEP();
    if (ph + 2 <= qt) LOADK(ph + 2);
    if (ph == 0 && pq == 0 && hi == 0) pre0 = st[0];  // (q, p=0) element

#pragma unroll 1
    for (int t = ph; t <= qt; t += 2) {
      const int D0 = qpb - 64 * t;
      const float B0 = (1.0f - (float)D0) * T_L;
      float d4_[4] = {0.f, 0.f, 0.f, 0.f};
      float s4_[4] = {0.f, 0.f, 0.f, 0.f};
      if (t == qt) {  // diagonal/masked tile (wave-uniform branch)
#pragma unroll
        for (int r = 0; r < 16; ++r) {
          const int ro = (r & 3) + 8 * (r >> 2);
          const float pre = st[r];
          float b2 = B0 + (float)ro * T_L;
          b2 = (D0 == ro) ? T_DIAG : b2;
          b2 = (D0 < ro) ? -1e38f : b2;
          st[r] = T_EXP(fmaf(0.125f, T_LOG(pre + 1e-20f), b2));
          d4_[r & 3] += st[r];
          s4_[r & 3] += (D0 >= ro) ? pre : 0.f;
        }
      } else {  // interior: d >= 1 everywhere, mask-free
#pragma unroll
        for (int r = 0; r < 16; ++r) {
          const int ro = (r & 3) + 8 * (r >> 2);
          const float pre = st[r];
          const float b2 = B0 + (float)ro * T_L;
          st[r] = T_EXP(fmaf(0.125f, T_LOG(pre + 1e-20f), b2));
          d4_[r & 3] += st[r];
          s4_[r & 3] += pre;
        }
      }
      den += (d4_[0] + d4_[1]) + (d4_[2] + d4_[3]);
      srw += (s4_[0] + s4_[1]) + (s4_[2] + s4_[3]);
      unsigned P0 = cvtpk(st[0], st[1]), P1 = cvtpk(st[2], st[3]);
      unsigned P2 = cvtpk(st[4], st[5]), P3 = cvtpk(st[6], st[7]);
      unsigned P4 = cvtpk(st[8], st[9]), P5 = cvtpk(st[10], st[11]);
      unsigned P6 = cvtpk(st[12], st[13]), P7 = cvtpk(st[14], st[15]);
      if (t + 2 <= qt) {
        QKSTEP();  // st = S(t+2) from kK = K(t+2)
        if (t + 4 <= qt) LOADK(t + 4);
      }
      REPACK_PV();  // consumes vV = V(t)
      if (t + 2 <= qt) LOADV(t + 2);
    }
  }

  // ---- cross-wave reduction over (pq, ph) ----
  const float dsum = den + __shfl_xor(den, 32, 64);
  const float ssum = srw + __shfl_xor(srw, 32, 64);
  if (hi == 0) {
    rdn[wv][lm] = dsum;
    rsw[wv][lm] = ssum;
    if (wv == 0) rp0[lm] = pre0;
  }
  if (wv != 0) {
#pragma unroll
    for (int r = 0; r < 16; ++r) {
      const int row = (r & 3) + 8 * (r >> 2) + 4 * hi;
      nbuf[wv - 1][row][lm] = num0[r];
      nbuf[wv - 1][row][32 + lm] = num1[r];
    }
  }
  __syncthreads();
  if (wv == 0 && hi == 0) {
    const int q = lm;
    const float dtot = rdn[0][q] + rdn[1][q] + rdn[2][q] + rdn[3][q];
    const float stot = rsw[0][q] + rsw[1][q] + rsw[2][q] + rsw[3][q];
    const float p0v = rp0[q];
    const float ms = stot / (stot + 1e-10f);
    const float add = fmaxf(1.f - ms, 0.f);
    const int qgq = qt * 64 + qq * 32 + q;
    const float b8 =
        (qgq == 0) ? -0.25f : (1.0f - (float)qgq) * (0.125f / 1023.0f);
    const float w0n = __expf(fmaf(0.125f, __logf(p0v + add + 1e-20f), b8));
    const float w0o = __expf(fmaf(0.125f, __logf(p0v + 1e-20f), b8));
    const float dwv = w0n - w0o;
    rdw[q] = dwv;
    rinv[q] = 1.f / (dtot + dwv);
  }
  __syncthreads();
  if (wv == 0) {
#pragma unroll
    for (int r = 0; r < 16; ++r) {
      const int row = (r & 3) + 8 * (r >> 2) + 4 * hi;
      const int qgq = qt * 64 + qq * 32 + row;
      const float dwv = rdw[row];
      const float iv = rinv[row];
      const float o0 = (num0[r] + nbuf[0][row][lm] + nbuf[1][row][lm] +
                        nbuf[2][row][lm] + dwv * v0a) * iv;
      const float o1 = (num1[r] + nbuf[0][row][32 + lm] +
                        nbuf[1][row][32 + lm] + nbuf[2][row][32 + lm] +
                        dwv * v0b) * iv;
      float* op = out + ((size_t)b * NCTX + qgq) * DIN + ih * DH;
      op[lm] = o0;
      op[32 + lm] = o1;
    }
  }
#undef LOADK
#undef LOADV
#undef QKSTEP
#undef REPACK_PV
}

extern "C" void kernel_launch(void* const* d_in, const int* in_sizes, int n_in,
                              void* d_out, int out_size, void* d_ws,
                              size_t ws_size, hipStream_t stream) {
  const float* x = (const float*)d_in[0];
  const float* WKw = (const float*)d_in[2];
  const float* WQw = (const float*)d_in[3];
  const float* WVw = (const float*)d_in[4];
  const float* Wpred = (const float*)d_in[5];
  float* out = (float*)d_out;

  short* Qf = (short*)((char*)d_ws + QF_OFF);
  short* Kf = (short*)((char*)d_ws + KF_OFF);
  short* Vf = (short*)((char*)d_ws + VF_OFF);
  float* V0f = (float*)((char*)d_ws + V0_OFF);

  dim3 block(256);
  dim3 grid1(16, NH, 4);
  hipLaunchKernelGGL(prep_kernel, grid1, block, 0, stream, x, WKw, WQw, WVw,
                     Wpred, Qf, Kf, Vf, V0f);
  dim3 grid2(1024);
  hipLaunchKernelGGL(attn_kernel, grid2, block, 0, stream, Qf, Kf, Vf, V0f,
                     out);
}

// Round 18
// 31.192 us; speedup vs baseline: 1.1706x; 1.1706x over previous
//
#include <hip/hip_runtime.h>
#include <math.h>

#define NCTX 1024
#define DIN 512
#define NH 8
#define DH 64

typedef float f32x16 __attribute__((ext_vector_type(16)));
typedef short bf16x8 __attribute__((ext_vector_type(8)));
typedef int i32x4 __attribute__((ext_vector_type(4)));

// ws byte offsets: Qf 4MB | Kf 4MB | Vf 4MB | V0f 8KB
#define QF_OFF 0
#define KF_OFF (4u * 1024u * 1024u)
#define VF_OFF (8u * 1024u * 1024u)
#define V0_OFF (12u * 1024u * 1024u)

__device__ __forceinline__ bf16x8 asbf(i32x4 v) {
  union { i32x4 i; bf16x8 h; } u;
  u.i = v;
  return u.h;
}

__device__ __forceinline__ bf16x8 mk8(unsigned a, unsigned b, unsigned c,
                                      unsigned d) {
  union { unsigned u[4]; bf16x8 h; } x;
  x.u[0] = a; x.u[1] = b; x.u[2] = c; x.u[3] = d;
  return x.h;
}

__device__ __forceinline__ unsigned cvtpk(float lo, float hi_) {
  unsigned r;
  asm("v_cvt_pk_bf16_f32 %0, %1, %2" : "=v"(r) : "v"(lo), "v"(hi_));
  return r;
}

__device__ __forceinline__ void softmax8(const float* __restrict__ w,
                                         float* __restrict__ p) {
  float mx = w[0];
#pragma unroll
  for (int v = 1; v < 8; ++v) mx = fmaxf(mx, w[v]);
  float s = 0.f;
#pragma unroll
  for (int v = 0; v < 8; ++v) { p[v] = expf(w[v] - mx); s += p[v]; }
  const float inv = 1.f / s;
#pragma unroll
  for (int v = 0; v < 8; ++v) p[v] *= inv;
}

// Fragment layouts:
// Kf[bi][t][pq][kk][lane] : K[32pq+l%32][16kk+8*(l>>5)+i]   (A-op of St)
// Qf[bi][t][qq][kk][lane] : Q[32qq+l%32][16kk+8*(l>>5)+i]   (B-op of St)
// Vf[bi][t][pq][2kk2+hh][lane] : V[32pq+16kk2+8*(l>>5)+i][32hh+l%32] (B-op PV)
__global__ __launch_bounds__(256) void prep_kernel(
    const float* __restrict__ x, const float* __restrict__ WKw,
    const float* __restrict__ WQw, const float* __restrict__ WVw,
    const float* __restrict__ Wpred, short* __restrict__ Qf,
    short* __restrict__ Kf, short* __restrict__ Vf, float* __restrict__ V0f) {
  const int t = blockIdx.x, ih = blockIdx.y, b = blockIdx.z;
  const int bi = b * NH + ih;
  const int tid = threadIdx.x;

  // bf16 tiles, 128B rows, XOR-swizzled: byte = row*128 + (col2 ^ ((row&7)<<4))
  __shared__ alignas(16) char smem[5 * 8192];
  char* const Ksb = smem;              // K row-major [p][h]
  char* const Vtb = smem + 8192;       // V col-major [h][p]
  char* const Q0b = smem + 16384;      // Q0 row-major [q][e]
  char* const WpT = smem + 24576;      // Wp transposed [f][e]
  char* const Qsb = smem + 32768;      // Q row-major [q][f]

  // ---- Wp softmax -> WpT (transposed, bf16, swizzled) ----
  {
    const int e = tid >> 2, sg = tid & 3;
    const float* wr = Wpred + (size_t)(ih * 64 + e) * 64 + sg * 16;
    float e16[16];
    float mx = -1e30f;
#pragma unroll
    for (int j = 0; j < 16; ++j) { e16[j] = wr[j]; mx = fmaxf(mx, e16[j]); }
    mx = fmaxf(mx, __shfl_xor(mx, 1, 4));
    mx = fmaxf(mx, __shfl_xor(mx, 2, 4));
    float s = 0.f;
#pragma unroll
    for (int j = 0; j < 16; ++j) { e16[j] = __expf(e16[j] - mx); s += e16[j]; }
    s += __shfl_xor(s, 1, 4);
    s += __shfl_xor(s, 2, 4);
    const float inv = 1.f / s;
#pragma unroll
    for (int j = 0; j < 16; ++j) {
      const int f = sg * 16 + j;
      const unsigned pz = cvtpk(e16[j] * inv, e16[j] * inv);
      *(unsigned short*)&WpT[f * 128 + ((2 * e) ^ ((f & 7) << 4))] =
          (unsigned short)pz;
    }
  }

  float pk[8], pq8[8], pv[8];
  {
    float w[8];
#pragma unroll
    for (int v = 0; v < 8; ++v) w[v] = WKw[ih * 8 + v];
    softmax8(w, pk);
#pragma unroll
    for (int v = 0; v < 8; ++v) w[v] = WQw[ih * 8 + v];
    softmax8(w, pq8);
#pragma unroll
    for (int v = 0; v < 8; ++v) w[v] = WVw[ih * 8 + v];
    softmax8(w, pv);
  }

  // ---- Stage A: 4x4 register block of the mixes, float4 x loads ----
  const int rg = tid >> 4, eg = tid & 15;
  const int r0 = rg * 4, e0 = eg * 4;
  float ka[4][4], qa[4][4], va[4][4];
#pragma unroll
  for (int i2 = 0; i2 < 4; ++i2)
#pragma unroll
    for (int j = 0; j < 4; ++j) { ka[i2][j] = 0.f; qa[i2][j] = 0.f; va[i2][j] = 0.f; }

  const float* xb = x + ((size_t)(b * NCTX + t * 64 + r0)) * DIN + e0;
#pragma unroll
  for (int v = 0; v < 8; ++v) {
#pragma unroll
    for (int i2 = 0; i2 < 4; ++i2) {
      const float4 xv = *(const float4*)(xb + (size_t)i2 * DIN + v * 64);
      ka[i2][0] = fmaf(pk[v], xv.x, ka[i2][0]);
      ka[i2][1] = fmaf(pk[v], xv.y, ka[i2][1]);
      ka[i2][2] = fmaf(pk[v], xv.z, ka[i2][2]);
      ka[i2][3] = fmaf(pk[v], xv.w, ka[i2][3]);
      qa[i2][0] = fmaf(pq8[v], xv.x, qa[i2][0]);
      qa[i2][1] = fmaf(pq8[v], xv.y, qa[i2][1]);
      qa[i2][2] = fmaf(pq8[v], xv.z, qa[i2][2]);
      qa[i2][3] = fmaf(pq8[v], xv.w, qa[i2][3]);
      va[i2][0] = fmaf(pv[v], xv.x, va[i2][0]);
      va[i2][1] = fmaf(pv[v], xv.y, va[i2][1]);
      va[i2][2] = fmaf(pv[v], xv.z, va[i2][2]);
      va[i2][3] = fmaf(pv[v], xv.w, va[i2][3]);
    }
  }

  // V[0][*] in f32 for the attn correction term
  if (t == 0 && rg == 0) {
    *(float4*)(V0f + bi * 64 + e0) =
        make_float4(va[0][0], va[0][1], va[0][2], va[0][3]);
  }

  // bf16 LDS writes (K, Q0 row-major; V col-major)
#pragma unroll
  for (int i2 = 0; i2 < 4; ++i2) {
    const int r = r0 + i2;
    const int boff = (2 * e0) ^ ((r & 7) << 4);
    *(uint2*)&Ksb[r * 128 + boff] =
        make_uint2(cvtpk(ka[i2][0], ka[i2][1]), cvtpk(ka[i2][2], ka[i2][3]));
    *(uint2*)&Q0b[r * 128 + boff] =
        make_uint2(cvtpk(qa[i2][0], qa[i2][1]), cvtpk(qa[i2][2], qa[i2][3]));
  }
#pragma unroll
  for (int j = 0; j < 4; ++j) {
    const int rr = e0 + j;
    *(uint2*)&Vtb[rr * 128 + ((2 * r0) ^ ((rr & 7) << 4))] =
        make_uint2(cvtpk(va[0][j], va[1][j]), cvtpk(va[2][j], va[3][j]));
  }
  __syncthreads();

  const int wv = tid >> 6;
  const int l = tid & 63;
  const int lm = l & 31;
  const int hi = l >> 5;

  // ---- K/V fragment emission ----
  const size_t fbase = (size_t)bi * 8192 + (size_t)t * 512;
#pragma unroll
  for (int c = 0; c < 2; ++c) {
    const int idx = c * 256 + tid;
    const int pq = idx >> 8, j = (idx >> 6) & 3, ll = idx & 63;
    const int krow = 32 * pq + (ll & 31);
    const i32x4 kfr = *(const i32x4*)
        &Ksb[krow * 128 + ((32 * j + 16 * (ll >> 5)) ^ ((krow & 7) << 4))];
    ((i32x4*)Kf)[fbase + idx] = kfr;
    const int vrow = 32 * (j & 1) + (ll & 31);
    const i32x4 vfr = *(const i32x4*)
        &Vtb[vrow * 128 +
             ((64 * pq + 32 * (j >> 1) + 16 * (ll >> 5)) ^ ((vrow & 7) << 4))];
    ((i32x4*)Vf)[fbase + idx] = vfr;
  }

  // ---- Q = Q0 @ Wp via MFMA (wave quadrant qq x ff) ----
  {
    const int qq = wv & 1, ff = wv >> 1;
    f32x16 dreg;
#pragma unroll
    for (int r = 0; r < 16; ++r) dreg[r] = 0.f;
    const int arow = 32 * qq + lm;
    const int brow = 32 * ff + lm;
#pragma unroll
    for (int kk = 0; kk < 4; ++kk) {
      const i32x4 af = *(const i32x4*)
          &Q0b[arow * 128 + ((32 * kk + 16 * hi) ^ ((arow & 7) << 4))];
      const i32x4 bfr = *(const i32x4*)
          &WpT[brow * 128 + ((32 * kk + 16 * hi) ^ ((brow & 7) << 4))];
      dreg = __builtin_amdgcn_mfma_f32_32x32x16_bf16(asbf(af), asbf(bfr),
                                                     dreg, 0, 0, 0);
    }
#pragma unroll
    for (int r = 0; r < 16; ++r) {
      const int q = 32 * qq + (r & 3) + 8 * (r >> 2) + 4 * hi;
      const int f = 32 * ff + lm;
      const unsigned pz = cvtpk(dreg[r], dreg[r]);
      *(unsigned short*)&Qsb[q * 128 + ((2 * f) ^ ((q & 7) << 4))] =
          (unsigned short)pz;
    }
  }
  __syncthreads();

  // ---- Q fragment emission ----
#pragma unroll
  for (int c = 0; c < 2; ++c) {
    const int idx = c * 256 + tid;
    const int qq2 = idx >> 8, kk = (idx >> 6) & 3, ll = idx & 63;
    const int row = 32 * qq2 + (ll & 31);
    const i32x4 qfr = *(const i32x4*)
        &Qsb[row * 128 + ((32 * kk + 16 * (ll >> 5)) ^ ((row & 7) << 4))];
    ((i32x4*)Qf)[fbase + idx] = qfr;
  }
}

// Transform constants: log2 domain if the raw builtins exist, else natural.
#if __has_builtin(__builtin_amdgcn_exp2f) && __has_builtin(__builtin_amdgcn_logf)
#define T_LOG(x) __builtin_amdgcn_logf(x)
#define T_EXP(x) __builtin_amdgcn_exp2f(x)
#define T_L 1.7628215e-4f   /* 0.125/(1023*ln2) */
#define T_DIAG (-0.36067376f) /* -0.25*log2(e) */
#else
#define T_LOG(x) __logf(x)
#define T_EXP(x) __expf(x)
#define T_L 1.2219941e-4f   /* 0.125/1023 */
#define T_DIAG (-0.25f)
#endif

// Kernel 2: MFMA attention — FINAL (r9/r16 configuration, 31.32/31.34us,
// reproduced across sessions; every structural alternative measured worse).
// 512 blocks x 256 thr; bx>>5 -> qt (heavy 15..8 then light 0..7) so CU c
// holds {c, c+256} = 17 steps. Waves: pq = wv&1, qq = wv>>1.
// Single st accumulator (transform in place, QK(t+1) overwrites), K/V
// single-buffered. KEEPS the srw/pre0 side-chain + epsilons: removing them
// costs +3.3us (r15 vs r16 — the independent adds pad the serial log->exp
// chain). NO occupancy attributes (r6/r8/r17 all regressed).
__global__ __launch_bounds__(256) void attn_kernel(
    const short* __restrict__ Qf, const short* __restrict__ Kf,
    const short* __restrict__ Vf, const float* __restrict__ V0f,
    float* __restrict__ out) {
  const int bx = blockIdx.x;
  const int a = bx >> 5;
  const int bi = bx & 31;
  const int qt = (a < 8) ? (15 - a) : (a - 8);
  const int b = bi >> 3, ih = bi & 7;
  const int tid = threadIdx.x;
  const int wv = tid >> 6;
  const int l = tid & 63;
  const int hi = l >> 5;
  const int lm = l & 31;
  const int pq = wv & 1;
  const int qq = wv >> 1;

  __shared__ float num_l[2][32][64];
  __shared__ float rdn[2][2][32];
  __shared__ float rsw[2][2][32];
  __shared__ float rp0[2][32];
  __shared__ float rdw[2][32];
  __shared__ float rinv[2][32];

  const i32x4* Qp = (const i32x4*)Qf + (size_t)bi * 8192 + (size_t)qt * 512 +
                    qq * 256;
  const i32x4* Kp = (const i32x4*)Kf + (size_t)bi * 8192 + pq * 256;
  const i32x4* Vp = (const i32x4*)Vf + (size_t)bi * 8192 + pq * 256;

  bf16x8 qfr[4];
#pragma unroll
  for (int kk = 0; kk < 4; ++kk) qfr[kk] = asbf(Qp[kk * 64 + l]);

  const float v0a = V0f[bi * 64 + lm];
  const float v0b = V0f[bi * 64 + 32 + lm];

  f32x16 num0, num1, st;
#pragma unroll
  for (int r = 0; r < 16; ++r) { num0[r] = 0.f; num1[r] = 0.f; }
  float den = 0.f, srw = 0.f, pre0 = 0.f;
  const int qg = qt * 64 + 32 * qq + lm;
  const int qpb = qg - 32 * pq - 4 * hi;  // D0 = qpb - 64*t

  i32x4 kK[4], vV[4];

#define LOADK(PT)                                                       \
  do {                                                                  \
    const size_t o_ = (size_t)(PT) * 512;                               \
    _Pragma("unroll") for (int kk = 0; kk < 4; ++kk)                    \
        kK[kk] = Kp[o_ + kk * 64 + l];                                  \
  } while (0)

#define LOADV(PT)                                                       \
  do {                                                                  \
    const size_t o_ = (size_t)(PT) * 512;                               \
    _Pragma("unroll") for (int j = 0; j < 4; ++j)                       \
        vV[j] = Vp[o_ + j * 64 + l];                                    \
  } while (0)

#define QKSTEP()                                                             \
  do {                                                                       \
    _Pragma("unroll") for (int r = 0; r < 16; ++r) st[r] = 0.f;              \
    __builtin_amdgcn_s_setprio(1);                                           \
    _Pragma("unroll") for (int kk = 0; kk < 4; ++kk) st =                    \
        __builtin_amdgcn_mfma_f32_32x32x16_bf16(asbf(kK[kk]), qfr[kk],       \
                                                st, 0, 0, 0);                \
    __builtin_amdgcn_s_setprio(0);                                           \
  } while (0)

#define REPACK_PV()                                                          \
  do {                                                                       \
    asm("v_permlane32_swap_b32 %0, %1" : "+v"(P0), "+v"(P2));                \
    asm("v_permlane32_swap_b32 %0, %1" : "+v"(P1), "+v"(P3));                \
    asm("v_permlane32_swap_b32 %0, %1" : "+v"(P4), "+v"(P6));                \
    asm("v_permlane32_swap_b32 %0, %1" : "+v"(P5), "+v"(P7));                \
    const bf16x8 wf0 = mk8(P0, P1, P2, P3);                                  \
    const bf16x8 wf1 = mk8(P4, P5, P6, P7);                                  \
    __builtin_amdgcn_s_setprio(1);                                           \
    num0 = __builtin_amdgcn_mfma_f32_32x32x16_bf16(wf0, asbf(vV[0]),         \
                                                   num0, 0, 0, 0);           \
    num1 = __builtin_amdgcn_mfma_f32_32x32x16_bf16(wf0, asbf(vV[1]),         \
                                                   num1, 0, 0, 0);           \
    num0 = __builtin_amdgcn_mfma_f32_32x32x16_bf16(wf1, asbf(vV[2]),         \
                                                   num0, 0, 0, 0);           \
    num1 = __builtin_amdgcn_mfma_f32_32x32x16_bf16(wf1, asbf(vV[3]),         \
                                                   num1, 0, 0, 0);           \
    __builtin_amdgcn_s_setprio(0);                                           \
  } while (0)

  // Prologue: establish invariant for t=0.
  LOADK(0);
  LOADV(0);
  QKSTEP();  // st = S(0)
  if (qt >= 1) LOADK(1);
  if (pq == 0 && hi == 0) pre0 = st[0];  // S(0)[r=0] is the (q, p=0) element

  // Interior iterations: d >= 1 everywhere -> mask-free transform.
#pragma unroll 1
  for (int t = 0; t < qt; ++t) {
    const int D0 = qpb - 64 * t;
    const float B0 = (1.0f - (float)D0) * T_L;
    {
      float d4_[4] = {0.f, 0.f, 0.f, 0.f};
      float s4_[4] = {0.f, 0.f, 0.f, 0.f};
#pragma unroll
      for (int r = 0; r < 16; ++r) {
        const int ro = (r & 3) + 8 * (r >> 2);
        const float pre = st[r];
        const float b2 = B0 + (float)ro * T_L;
        st[r] = T_EXP(fmaf(0.125f, T_LOG(pre + 1e-20f), b2));
        d4_[r & 3] += st[r];
        s4_[r & 3] += pre;
      }
      den += (d4_[0] + d4_[1]) + (d4_[2] + d4_[3]);
      srw += (s4_[0] + s4_[1]) + (s4_[2] + s4_[3]);
    }
    unsigned P0 = cvtpk(st[0], st[1]), P1 = cvtpk(st[2], st[3]);
    unsigned P2 = cvtpk(st[4], st[5]), P3 = cvtpk(st[6], st[7]);
    unsigned P4 = cvtpk(st[8], st[9]), P5 = cvtpk(st[10], st[11]);
    unsigned P6 = cvtpk(st[12], st[13]), P7 = cvtpk(st[14], st[15]);
    QKSTEP();  // st = S(t+1) from kK = K(t+1)
    if (t + 2 <= qt) LOADK(t + 2);
    REPACK_PV();  // consumes vV = V(t)
    LOADV(t + 1);
  }

  // Diagonal tile t = qt (masked path).
  {
    const int D0 = qpb - 64 * qt;
    const float B0 = (1.0f - (float)D0) * T_L;
    float d4_[4] = {0.f, 0.f, 0.f, 0.f};
    float s4_[4] = {0.f, 0.f, 0.f, 0.f};
#pragma unroll
    for (int r = 0; r < 16; ++r) {
      const int ro = (r & 3) + 8 * (r >> 2);
      const float pre = st[r];
      float b2 = B0 + (float)ro * T_L;
      b2 = (D0 == ro) ? T_DIAG : b2;
      b2 = (D0 < ro) ? -1e38f : b2;
      st[r] = T_EXP(fmaf(0.125f, T_LOG(pre + 1e-20f), b2));
      d4_[r & 3] += st[r];
      s4_[r & 3] += (D0 >= ro) ? pre : 0.f;
    }
    den += (d4_[0] + d4_[1]) + (d4_[2] + d4_[3]);
    srw += (s4_[0] + s4_[1]) + (s4_[2] + s4_[3]);
    unsigned P0 = cvtpk(st[0], st[1]), P1 = cvtpk(st[2], st[3]);
    unsigned P2 = cvtpk(st[4], st[5]), P3 = cvtpk(st[6], st[7]);
    unsigned P4 = cvtpk(st[8], st[9]), P5 = cvtpk(st[10], st[11]);
    unsigned P6 = cvtpk(st[12], st[13]), P7 = cvtpk(st[14], st[15]);
    REPACK_PV();
  }

  // cross-wave (pq) reduction
  const float dsum = den + __shfl_xor(den, 32, 64);
  const float ssum = srw + __shfl_xor(srw, 32, 64);
  if (hi == 0) {
    rdn[qq][pq][lm] = dsum;
    rsw[qq][pq][lm] = ssum;
    if (pq == 0) rp0[qq][lm] = pre0;
  }
  if (pq == 1) {
#pragma unroll
    for (int r = 0; r < 16; ++r) {
      const int row = (r & 3) + 8 * (r >> 2) + 4 * hi;
      num_l[qq][row][lm] = num0[r];
      num_l[qq][row][32 + lm] = num1[r];
    }
  }
  __syncthreads();
  if (pq == 1 && hi == 0) {
    const int q = lm;
    const float dtot = rdn[qq][0][q] + rdn[qq][1][q];
    const float stot = rsw[qq][0][q] + rsw[qq][1][q];
    const float p0v = rp0[qq][q];
    const float ms = stot / (stot + 1e-10f);
    const float add = fmaxf(1.f - ms, 0.f);
    const int qgq = qt * 64 + qq * 32 + q;
    const float b8 =
        (qgq == 0) ? -0.25f : (1.0f - (float)qgq) * (0.125f / 1023.0f);
    const float w0n = __expf(fmaf(0.125f, __logf(p0v + add + 1e-20f), b8));
    const float w0o = __expf(fmaf(0.125f, __logf(p0v + 1e-20f), b8));
    const float dwv = w0n - w0o;
    rdw[qq][q] = dwv;
    rinv[qq][q] = 1.f / (dtot + dwv);
  }
  __syncthreads();
  if (pq == 0) {
#pragma unroll
    for (int r = 0; r < 16; ++r) {
      const int row = (r & 3) + 8 * (r >> 2) + 4 * hi;
      const int qgq = qt * 64 + qq * 32 + row;
      const float dwv = rdw[qq][row];
      const float iv = rinv[qq][row];
      const float o0 = (num0[r] + num_l[qq][row][lm] + dwv * v0a) * iv;
      const float o1 = (num1[r] + num_l[qq][row][32 + lm] + dwv * v0b) * iv;
      float* op = out + ((size_t)b * NCTX + qgq) * DIN + ih * DH;
      op[lm] = o0;
      op[32 + lm] = o1;
    }
  }
#undef LOADK
#undef LOADV
#undef QKSTEP
#undef REPACK_PV
}

extern "C" void kernel_launch(void* const* d_in, const int* in_sizes, int n_in,
                              void* d_out, int out_size, void* d_ws,
                              size_t ws_size, hipStream_t stream) {
  const float* x = (const float*)d_in[0];
  const float* WKw = (const float*)d_in[2];
  const float* WQw = (const float*)d_in[3];
  const float* WVw = (const float*)d_in[4];
  const float* Wpred = (const float*)d_in[5];
  float* out = (float*)d_out;

  short* Qf = (short*)((char*)d_ws + QF_OFF);
  short* Kf = (short*)((char*)d_ws + KF_OFF);
  short* Vf = (short*)((char*)d_ws + VF_OFF);
  float* V0f = (float*)((char*)d_ws + V0_OFF);

  dim3 block(256);
  dim3 grid1(16, NH, 4);
  hipLaunchKernelGGL(prep_kernel, grid1, block, 0, stream, x, WKw, WQw, WVw,
                     Wpred, Qf, Kf, Vf, V0f);
  dim3 block2(256);
  dim3 grid2(512);
  hipLaunchKernelGGL(attn_kernel, grid2, block2, 0, stream, Qf, Kf, Vf, V0f,
                     out);
}